// Round 14
// baseline (135.803 us; speedup 1.0000x reference)
//
#include <hip/hip_runtime.h>

#define BB 8
#define CC 384
#define HH 64
#define WW 64
#define NH 6
#define HD 64
#define PLANE (HH*WW)        /* 4096 */
#define QKSCALE 0.125f
#define CH_B  (PLANE*4)      /* 16384 bytes per channel step */
#define CHUNK_B (8*CH_B)     /* 131072 bytes per 8-channel chunk */

typedef float f32x4 __attribute__((ext_vector_type(4)));
typedef int   i32x4 __attribute__((ext_vector_type(4)));

__device__ __forceinline__ i32x4 make_srsrc(const void* p) {
  union { unsigned long long a; int w[2]; } u; u.a = (unsigned long long)p;
  i32x4 r; r.x = u.w[0]; r.y = u.w[1]; r.z = -1 /*num_records: disable*/; r.w = 0x00020000;
  return r;
}

// buffer_load_dword: dst <- rsrc[voff + soff]; counted by vmcnt, issue order pinned.
__device__ __forceinline__ void bl(float& dst, i32x4 rsrc, int voff, int soff) {
  asm volatile("buffer_load_dword %0, %1, %2, %3 offen"
               : "=v"(dst) : "v"(voff), "s"(rsrc), "s"(soff));
}

__device__ __forceinline__ void issue_q8(float (&qb)[8], i32x4 rq, int voq) {
#pragma unroll
  for (int dd = 0; dd < 8; ++dd) bl(qb[dd], rq, voq, dd * CH_B);
}
// CHANNEL-MAJOR issue: rows y-1,y,y+1 of one channel are 256B apart in memory,
// so back-to-back issue presents 768B-contiguous granules to DRAM (vs 3 visits
// 16KB apart in the old row-major order). Buffer layout: kb[dd*3 + r].
__device__ __forceinline__ void issue_r24(float (&kb)[24], i32x4 rk, int vo0, int vo1, int vo2) {
#pragma unroll
  for (int dd = 0; dd < 8; ++dd) {
    bl(kb[dd * 3 + 0], rk, vo0, dd * CH_B);
    bl(kb[dd * 3 + 1], rk, vo1, dd * CH_B);
    bl(kb[dd * 3 + 2], rk, vo2, dd * CH_B);
  }
}

__global__ __launch_bounds__(256, 2) void dilate_attn_kernel(
    const float* __restrict__ qg, const float* __restrict__ kg,
    const float* __restrict__ vg, float* __restrict__ outg) {
  // bijective XCD swizzle: 768 blocks, 96 per XCD, consecutive y-strips per XCD
  const int blk  = (blockIdx.x % 8) * 96 + (blockIdx.x / 8);
  const int nyb  = HH / 4;
  const int y0   = (blk % nyb) * 4;
  const int bh   = blk / nyb;          // b*NH + head
  const int head = bh % NH;
  const int b    = bh / NH;
  const int lane = threadIdx.x & 63;
  const int warp = threadIdx.x >> 6;
  const int y = y0 + warp;
  const int x = lane;

  const int laneL = (lane - 1) & 63;   // srcLane for x-1 (wraps onto masked zeros)
  const int laneR = (lane + 1) & 63;   // srcLane for x+1

  const i32x4 rq = make_srsrc(qg);
  const i32x4 rk = make_srsrc(kg);
  const i32x4 rv = make_srsrc(vg);

  const int slab4 = (b * CC + head * HD) * (PLANE * 4);   // byte base of this head's slab
  const int voq = slab4 + (y * WW + x) * 4;

  int vor[3];   // per-row byte offsets (shared by k and v)
  float m[9];
#pragma unroll
  for (int r = 0; r < 3; ++r) {
    const int yy = y + r - 1;
    const int yc = min(max(yy, 0), HH - 1);
    vor[r] = slab4 + (yc * WW + x) * 4;
    const bool rowok = (yy >= 0) && (yy < HH);
#pragma unroll
    for (int dx = 0; dx < 3; ++dx) {
      const int xx = x + dx - 1;
      m[r * 3 + dx] = (rowok && xx >= 0 && xx < WW) ? 1.0f : 0.0f;
    }
  }

  // ---- QK^T: t[r][dx](x) = sum_d k_r,d(x) * q_d(x - dx) ----
  // 8 chunks x 8 channels, depth-2 double buffer, loads-only counted waits.
  float t[9];
#pragma unroll
  for (int i = 0; i < 9; ++i) t[i] = 0.0f;

  float qb[2][8], kb[2][24];
  issue_q8(qb[0], rq, voq);
  issue_r24(kb[0], rk, vor[0], vor[1], vor[2]);

#pragma unroll
  for (int c = 0; c < 8; ++c) {
    const int cur = c & 1, nxt = cur ^ 1;
    if (c < 7) {
      issue_q8(qb[nxt], rq, voq + (c + 1) * CHUNK_B);
      issue_r24(kb[nxt], rk, vor[0] + (c + 1) * CHUNK_B,
                             vor[1] + (c + 1) * CHUNK_B,
                             vor[2] + (c + 1) * CHUNK_B);
    }
    // q(cur) ready: newer LOADS = k(cur)24 [+ q(nxt)8 + k(nxt)24]
    if (c < 7) { asm volatile("s_waitcnt vmcnt(56)" ::: "memory"); }
    else       { asm volatile("s_waitcnt vmcnt(24)" ::: "memory"); }
    __builtin_amdgcn_sched_barrier(0);
    float qm[8], qp[8];
#pragma unroll
    for (int dd = 0; dd < 8; ++dd) {
      qm[dd] = __shfl(qb[cur][dd], laneL);  // q(x-1)
      qp[dd] = __shfl(qb[cur][dd], laneR);  // q(x+1)
    }
    // k(cur) ready: newer LOADS = [q(nxt)8 + k(nxt)24]
    if (c < 7) { asm volatile("s_waitcnt vmcnt(32)" ::: "memory"); }
    else       { asm volatile("s_waitcnt vmcnt(0)"  ::: "memory"); }
    __builtin_amdgcn_sched_barrier(0);
#pragma unroll
    for (int dd = 0; dd < 8; ++dd) {
#pragma unroll
      for (int r = 0; r < 3; ++r) {
        const float kc = kb[cur][dd * 3 + r];
        t[r * 3 + 0] = fmaf(kc, qp[dd], t[r * 3 + 0]);       // dx=-1 uses q(x+1)
        t[r * 3 + 1] = fmaf(kc, qb[cur][dd], t[r * 3 + 1]);  // dx= 0
        t[r * 3 + 2] = fmaf(kc, qm[dd], t[r * 3 + 2]);       // dx=+1 uses q(x-1)
      }
    }
  }

  // ---- issue PV chunk 0; it flies under the softmax ----
  float vb[2][24];
  issue_r24(vb[0], rv, vor[0], vor[1], vor[2]);

  // gather scores: s[r,dx](x) = t[r,dx](x+dx), mask, scale
  float s[9];
#pragma unroll
  for (int i = 0; i < 9; ++i) {
    const int dx = (i % 3) - 1;
    s[i] = __shfl(t[i], (lane + dx) & 63) * m[i] * QKSCALE;
  }
  // softmax over 9 (masked entries exactly 0, matching zero-padded ref)
  float mx = s[0];
#pragma unroll
  for (int i = 1; i < 9; ++i) mx = fmaxf(mx, s[i]);
  float sum = 0.0f;
#pragma unroll
  for (int i = 0; i < 9; ++i) { s[i] = __expf(s[i] - mx); sum += s[i]; }
  const float inv = 1.0f / sum;
#pragma unroll
  for (int i = 0; i < 9; ++i) s[i] = s[i] * inv * m[i];  // fold v-pad mask into p

  // pre-shift p: P[r,dx](j) = p[r,dx](j - dx); wrap lands on masked zeros
  float P[9];
#pragma unroll
  for (int i = 0; i < 9; ++i) {
    const int dx = (i % 3) - 1;
    P[i] = __shfl(s[i], (lane - dx) & 63);
  }

  // ---- PV: c_dx(j) = sum_r P[r,dx](j)*v_r(j); out(x) = sum_dx c_dx(x+dx) ----
  // Compiler stores trickled per chunk; NON-TEMPORAL so the 50MB output stream
  // doesn't evict q/k/v from L3 (raises read-hit rate on warm replays).
  float* outp = outg + ((long)((b * HH + y) * WW + x)) * CC + head * HD;

#pragma unroll
  for (int c = 0; c < 8; ++c) {
    const int cur = c & 1, nxt = cur ^ 1;
    if (c < 7) issue_r24(vb[nxt], rv, vor[0] + (c + 1) * CHUNK_B,
                                      vor[1] + (c + 1) * CHUNK_B,
                                      vor[2] + (c + 1) * CHUNK_B);
    // v(cur) ready <=> <= 24 newer v(nxt) loads outstanding (loads-only count;
    // interleaved compiler stores only lengthen the wait -> safe)
    if (c < 7) { asm volatile("s_waitcnt vmcnt(24)" ::: "memory"); }
    else       { asm volatile("s_waitcnt vmcnt(0)"  ::: "memory"); }
    __builtin_amdgcn_sched_barrier(0);

#pragma unroll
    for (int g = 0; g < 2; ++g) {
      f32x4 ov;
#pragma unroll
      for (int j = 0; j < 4; ++j) {
        const int dd = g * 4 + j;
        float cm = 0.f, cz = 0.f, cp = 0.f;
#pragma unroll
        for (int r = 0; r < 3; ++r) {
          const float vc = vb[cur][dd * 3 + r];
          cm = fmaf(P[r * 3 + 0], vc, cm);
          cz = fmaf(P[r * 3 + 1], vc, cz);
          cp = fmaf(P[r * 3 + 2], vc, cp);
        }
        ov[j] = cz + __shfl(cm, laneL) + __shfl(cp, laneR);
      }
      __builtin_nontemporal_store(ov, reinterpret_cast<f32x4*>(outp + c * 8 + g * 4));
    }
  }
}

extern "C" void kernel_launch(void* const* d_in, const int* in_sizes, int n_in,
                              void* d_out, int out_size, void* d_ws, size_t ws_size,
                              hipStream_t stream) {
  const float* q = (const float*)d_in[0];
  const float* k = (const float*)d_in[1];
  const float* v = (const float*)d_in[2];
  float* out = (float*)d_out;
  const int blocks = BB * NH * (HH / 4);  // 768
  dilate_attn_kernel<<<blocks, 256, 0, stream>>>(q, k, v, out);
}

// Round 15
// 41.326 us; speedup vs baseline: 3.2862x; 3.2862x over previous
//
#include <hip/hip_runtime.h>

#define BB 8
#define CC 384
#define HH 64
#define WW 64
#define NH 6
#define HD 64
#define PLANE (HH*WW)        /* 4096 */
#define QKSCALE 0.125f
#define CH_B  (PLANE*4)      /* 16384 bytes per channel step */
#define CHUNK_B (8*CH_B)     /* 131072 bytes per 8-channel chunk */

typedef float f32x4 __attribute__((ext_vector_type(4)));
typedef int   i32x4 __attribute__((ext_vector_type(4)));

__device__ __forceinline__ i32x4 make_srsrc(const void* p) {
  union { unsigned long long a; int w[2]; } u; u.a = (unsigned long long)p;
  i32x4 r; r.x = u.w[0]; r.y = u.w[1]; r.z = -1 /*num_records: disable*/; r.w = 0x00020000;
  return r;
}

// buffer_load_dword: dst <- rsrc[voff + soff]; counted by vmcnt, issue order pinned.
__device__ __forceinline__ void bl(float& dst, i32x4 rsrc, int voff, int soff) {
  asm volatile("buffer_load_dword %0, %1, %2, %3 offen"
               : "=v"(dst) : "v"(voff), "s"(rsrc), "s"(soff));
}

__device__ __forceinline__ void issue_q8(float (&qb)[8], i32x4 rq, int voq) {
#pragma unroll
  for (int dd = 0; dd < 8; ++dd) bl(qb[dd], rq, voq, dd * CH_B);
}
__device__ __forceinline__ void issue_r24(float (&kb)[24], i32x4 rk, int vo0, int vo1, int vo2) {
#pragma unroll
  for (int dd = 0; dd < 8; ++dd) bl(kb[0 * 8 + dd], rk, vo0, dd * CH_B);
#pragma unroll
  for (int dd = 0; dd < 8; ++dd) bl(kb[1 * 8 + dd], rk, vo1, dd * CH_B);
#pragma unroll
  for (int dd = 0; dd < 8; ++dd) bl(kb[2 * 8 + dd], rk, vo2, dd * CH_B);
}

__global__ __launch_bounds__(256, 3) void dilate_attn_kernel(
    const float* __restrict__ qg, const float* __restrict__ kg,
    const float* __restrict__ vg, float* __restrict__ outg) {
  // bijective XCD swizzle: 768 blocks, 96 per XCD, consecutive y-strips per XCD
  const int blk  = (blockIdx.x % 8) * 96 + (blockIdx.x / 8);
  const int nyb  = HH / 4;
  const int y0   = (blk % nyb) * 4;
  const int bh   = blk / nyb;          // b*NH + head
  const int head = bh % NH;
  const int b    = bh / NH;
  const int lane = threadIdx.x & 63;
  const int warp = threadIdx.x >> 6;
  const int y = y0 + warp;
  const int x = lane;

  const int laneL = (lane - 1) & 63;   // srcLane for x-1 (wraps onto masked zeros)
  const int laneR = (lane + 1) & 63;   // srcLane for x+1

  const i32x4 rq = make_srsrc(qg);
  const i32x4 rk = make_srsrc(kg);
  const i32x4 rv = make_srsrc(vg);

  const int slab4 = (b * CC + head * HD) * (PLANE * 4);   // byte base of this head's slab
  const int voq = slab4 + (y * WW + x) * 4;

  int vor[3];   // per-row byte offsets (shared by k and v)
  float m[9];
#pragma unroll
  for (int r = 0; r < 3; ++r) {
    const int yy = y + r - 1;
    const int yc = min(max(yy, 0), HH - 1);
    vor[r] = slab4 + (yc * WW + x) * 4;
    const bool rowok = (yy >= 0) && (yy < HH);
#pragma unroll
    for (int dx = 0; dx < 3; ++dx) {
      const int xx = x + dx - 1;
      m[r * 3 + dx] = (rowok && xx >= 0 && xx < WW) ? 1.0f : 0.0f;
    }
  }

  // ---- QK^T: t[r][dx](x) = sum_d k_r,d(x) * q_d(x - dx) ----
  // 8 chunks x 8 channels, depth-2 double buffer, loads-only counted waits.
  float t[9];
#pragma unroll
  for (int i = 0; i < 9; ++i) t[i] = 0.0f;

  float qb[2][8], kb[2][24];
  issue_q8(qb[0], rq, voq);
  issue_r24(kb[0], rk, vor[0], vor[1], vor[2]);

#pragma unroll
  for (int c = 0; c < 8; ++c) {
    const int cur = c & 1, nxt = cur ^ 1;
    if (c < 7) {
      issue_q8(qb[nxt], rq, voq + (c + 1) * CHUNK_B);
      issue_r24(kb[nxt], rk, vor[0] + (c + 1) * CHUNK_B,
                             vor[1] + (c + 1) * CHUNK_B,
                             vor[2] + (c + 1) * CHUNK_B);
    }
    // q(cur) ready: newer LOADS = k(cur)24 [+ q(nxt)8 + k(nxt)24]
    if (c < 7) { asm volatile("s_waitcnt vmcnt(56)" ::: "memory"); }
    else       { asm volatile("s_waitcnt vmcnt(24)" ::: "memory"); }
    __builtin_amdgcn_sched_barrier(0);
    float qm[8], qp[8];
#pragma unroll
    for (int dd = 0; dd < 8; ++dd) {
      qm[dd] = __shfl(qb[cur][dd], laneL);  // q(x-1)
      qp[dd] = __shfl(qb[cur][dd], laneR);  // q(x+1)
    }
    // k(cur) ready: newer LOADS = [q(nxt)8 + k(nxt)24]
    if (c < 7) { asm volatile("s_waitcnt vmcnt(32)" ::: "memory"); }
    else       { asm volatile("s_waitcnt vmcnt(0)"  ::: "memory"); }
    __builtin_amdgcn_sched_barrier(0);
#pragma unroll
    for (int dd = 0; dd < 8; ++dd) {
#pragma unroll
      for (int r = 0; r < 3; ++r) {
        const float kc = kb[cur][r * 8 + dd];
        t[r * 3 + 0] = fmaf(kc, qp[dd], t[r * 3 + 0]);       // dx=-1 uses q(x+1)
        t[r * 3 + 1] = fmaf(kc, qb[cur][dd], t[r * 3 + 1]);  // dx= 0
        t[r * 3 + 2] = fmaf(kc, qm[dd], t[r * 3 + 2]);       // dx=+1 uses q(x-1)
      }
    }
  }

  // ---- issue PV chunk 0; it flies under the softmax ----
  float vb[2][24];
  issue_r24(vb[0], rv, vor[0], vor[1], vor[2]);

  // gather scores: s[r,dx](x) = t[r,dx](x+dx), mask, scale
  float s[9];
#pragma unroll
  for (int i = 0; i < 9; ++i) {
    const int dx = (i % 3) - 1;
    s[i] = __shfl(t[i], (lane + dx) & 63) * m[i] * QKSCALE;
  }
  // softmax over 9 (masked entries exactly 0, matching zero-padded ref)
  float mx = s[0];
#pragma unroll
  for (int i = 1; i < 9; ++i) mx = fmaxf(mx, s[i]);
  float sum = 0.0f;
#pragma unroll
  for (int i = 0; i < 9; ++i) { s[i] = __expf(s[i] - mx); sum += s[i]; }
  const float inv = 1.0f / sum;
#pragma unroll
  for (int i = 0; i < 9; ++i) s[i] = s[i] * inv * m[i];  // fold v-pad mask into p

  // pre-shift p: P[r,dx](j) = p[r,dx](j - dx); wrap lands on masked zeros
  float P[9];
#pragma unroll
  for (int i = 0; i < 9; ++i) {
    const int dx = (i % 3) - 1;
    P[i] = __shfl(s[i], (lane - dx) & 63);
  }

  // ---- PV: c_dx(j) = sum_r P[r,dx](j)*v_r(j); out(x) = sum_dx c_dx(x+dx) ----
  // Compiler stores, inline per chunk (trickled, write-combine friendly).
  float* outp = outg + ((long)((b * HH + y) * WW + x)) * CC + head * HD;

#pragma unroll
  for (int c = 0; c < 8; ++c) {
    const int cur = c & 1, nxt = cur ^ 1;
    if (c < 7) issue_r24(vb[nxt], rv, vor[0] + (c + 1) * CHUNK_B,
                                      vor[1] + (c + 1) * CHUNK_B,
                                      vor[2] + (c + 1) * CHUNK_B);
    // v(cur) ready <=> <= 24 newer v(nxt) loads outstanding (loads-only count;
    // interleaved compiler stores only lengthen the wait -> safe)
    if (c < 7) { asm volatile("s_waitcnt vmcnt(24)" ::: "memory"); }
    else       { asm volatile("s_waitcnt vmcnt(0)"  ::: "memory"); }
    __builtin_amdgcn_sched_barrier(0);

#pragma unroll
    for (int g = 0; g < 2; ++g) {
      f32x4 ov;
#pragma unroll
      for (int j = 0; j < 4; ++j) {
        const int dd = g * 4 + j;
        float cm = 0.f, cz = 0.f, cp = 0.f;
#pragma unroll
        for (int r = 0; r < 3; ++r) {
          const float vc = vb[cur][r * 8 + dd];
          cm = fmaf(P[r * 3 + 0], vc, cm);
          cz = fmaf(P[r * 3 + 1], vc, cz);
          cp = fmaf(P[r * 3 + 2], vc, cp);
        }
        ov[j] = cz + __shfl(cm, laneL) + __shfl(cp, laneR);
      }
      *reinterpret_cast<f32x4*>(outp + c * 8 + g * 4) = ov;
    }
  }
}

extern "C" void kernel_launch(void* const* d_in, const int* in_sizes, int n_in,
                              void* d_out, int out_size, void* d_ws, size_t ws_size,
                              hipStream_t stream) {
  const float* q = (const float*)d_in[0];
  const float* k = (const float*)d_in[1];
  const float* v = (const float*)d_in[2];
  float* out = (float*)d_out;
  const int blocks = BB * NH * (HH / 4);  // 768
  dilate_attn_kernel<<<blocks, 256, 0, stream>>>(q, k, v, out);
}